// Round 7
// baseline (38506.787 us; speedup 1.0000x reference)
//
#include <hip/hip_runtime.h>

typedef unsigned int u32;
typedef unsigned long long u64;
typedef float f32x4 __attribute__((ext_vector_type(4)));

// np-bit-exact Leaky update: m' = f32(f32(f32(0.95f*m) + cur) - reset)
// reset from PREVIOUS mem; (mem-1>0) === (mem>1) exactly in f32 (Sterbenz).
__device__ __forceinline__ float leaky(float m, float cur) {
  float r = (m > 1.0f) ? 1.0f : 0.0f;
  return __fsub_rn(__fadd_rn(__fmul_rn(0.95f, m), cur), r);
}

// ---------------------------------------------------------------------------
// Phase A': cur1 (exact FMA chain, d ascending) + layer-1 sim; each lane
// accumulates the 25-step spike train of its 16 neurons (k = j*64+lane) as a
// 25-bit word, stored to masks2[s][k]. Same spike predicate as the verified
// ballot version; no lane-0 serialization.
// ---------------------------------------------------------------------------
__global__ __launch_bounds__(256) void k_spk1b(
    const float* __restrict__ x, const float* __restrict__ W1,
    const float* __restrict__ b1, u32* __restrict__ masks2,
    int s0, int Sc) {
  __shared__ float w1s[8 * 1024];
  const int tid = threadIdx.x, lane = tid & 63, w = tid >> 6;
  const int sl = blockIdx.x * 4 + w;
  const size_t s = (size_t)s0 + sl;

  float c1[16];
#pragma unroll
  for (int j = 0; j < 16; ++j) c1[j] = 0.0f;
#pragma unroll 1
  for (int ch = 0; ch < 8; ++ch) {
    __syncthreads();
#pragma unroll
    for (int it = 0; it < 8; ++it) {
      int v = tid + it * 256;
      *(f32x4*)(w1s + v * 4) =
          *(const f32x4*)(W1 + (size_t)(ch * 8 + (v >> 8)) * 1024 + (v & 255) * 4);
    }
    __syncthreads();
#pragma unroll 1
    for (int dl = 0; dl < 8; ++dl) {
      float xv = x[s * 64 + ch * 8 + dl];
#pragma unroll
      for (int j = 0; j < 16; ++j)
        c1[j] = fmaf(xv, w1s[dl * 1024 + j * 64 + lane], c1[j]);
    }
  }
#pragma unroll
  for (int j = 0; j < 16; ++j) c1[j] = __fadd_rn(c1[j], b1[j * 64 + lane]);

  float m1[16];
  u32 bits[16];
#pragma unroll
  for (int j = 0; j < 16; ++j) { m1[j] = 0.0f; bits[j] = 0u; }

#pragma unroll 1
  for (int t = 0; t < 25; ++t) {
    const u32 tb = 1u << t;
#pragma unroll
    for (int j = 0; j < 16; ++j) {
      m1[j] = leaky(m1[j], c1[j]);
      bits[j] |= (m1[j] > 1.0f) ? tb : 0u;
    }
  }
#pragma unroll
  for (int j = 0; j < 16; ++j)
    masks2[(size_t)sl * 1024 + j * 64 + lane] = bits[j];
}

// ---------------------------------------------------------------------------
// Phase B': FUSED layers 2+3. Wave = 1 sample. Stream all 1024 W2 rows ONCE
// per sample; gate each row into 25 per-step accumulators (time-axis
// amortization: 25 items share one row stream vs 8 before -> L2 traffic
// 410->131 GB, and cur2 never touches memory).
//   n-mapping: n = j*64+lane (8 scalars/lane), so ballots are n-ordered and
//   the verified k_tail chain applies unchanged.
//   Gates: per-neuron 25-bit word (readlane -> SGPR), g = bit_t ? 1.0f : 0.0f
//   wave-uniform scalar select; acc = fmaf(g, row, acc) — the proven exact
//   branchless chain (fma(0,w,c)=c, fma(1,w,c)=RN add), k ascending.
//   acc[25][8] / row arrays: ALL indices compile-time (full unroll) — no
//   dynamic indexing (rule #20). Branchy lane-0 chain isolated AFTER the
//   high-register region via LDS-staged ballots (r1/r2 failure mode avoided).
//   Prefetch: 4 row sets, issued 1-2 rows (>=400 fmaf-cycles) ahead.
// ---------------------------------------------------------------------------
#define LROW(R, KK) { const float* _p = wl + (size_t)(KK) * 512;          \
    _Pragma("unroll") for (int _j = 0; _j < 8; ++_j) R[_j] = _p[_j * 64]; }

#define PROW(R, WB) {                                                     \
    _Pragma("unroll") for (int _t = 0; _t < 25; ++_t) {                   \
      const float _g = ((WB) & (1u << _t)) ? 1.0f : 0.0f;                 \
      _Pragma("unroll") for (int _j = 0; _j < 8; ++_j)                    \
        acc[_t][_j] = fmaf(_g, R[_j], acc[_t][_j]); } }

__global__ __launch_bounds__(256, 1) void k_fused(
    const float* __restrict__ W2, const float* __restrict__ b2,
    const float* __restrict__ W3, const float* __restrict__ b3,
    const u32* __restrict__ masks2, float* __restrict__ out,
    int s0, int Sc) {
  __shared__ float w3s[512];
  __shared__ u64 sbuf[4][25][8];
  const int tid = threadIdx.x, lane = tid & 63, w = tid >> 6;
  const int sl = blockIdx.x * 4 + w;
  for (int i = tid; i < 512; i += 256) w3s[i] = W3[i];
  __syncthreads();

  float acc[25][8];
#pragma unroll
  for (int t = 0; t < 25; ++t)
#pragma unroll
    for (int j = 0; j < 8; ++j) acc[t][j] = 0.0f;

  const u32* mbase = masks2 + (size_t)sl * 1024;
  const float* wl = W2 + lane;          // W2[k][j*64+lane] at wl[k*512 + j*64]

  float ra[8], rb[8], rc[8], rd[8];
  LROW(ra, 0)
  LROW(rb, 1)

#pragma unroll 1
  for (int kw = 0; kw < 32; ++kw) {
    const u32 mw = mbase[kw * 32 + (lane & 31)];   // word for row kw*32+laneid
#pragma unroll 1
    for (int k2 = 0; k2 < 32; k2 += 4) {
      const int k = kw * 32 + k2;
      LROW(rc, k + 2)
      LROW(rd, k + 3)
      { const u32 wb = (u32)__builtin_amdgcn_readlane((int)mw, k2);     PROW(ra, wb) }
      { const u32 wb = (u32)__builtin_amdgcn_readlane((int)mw, k2 + 1); PROW(rb, wb) }
      const int k4 = (k + 4 < 1024) ? k + 4 : 1023;  // harmless clamp at tail
      const int k5 = (k + 5 < 1024) ? k + 5 : 1023;
      LROW(ra, k4)
      LROW(rb, k5)
      { const u32 wb = (u32)__builtin_amdgcn_readlane((int)mw, k2 + 2); PROW(rc, wb) }
      { const u32 wb = (u32)__builtin_amdgcn_readlane((int)mw, k2 + 3); PROW(rd, wb) }
    }
  }

  // ---- layer-2 recurrence in-register; ballots staged to LDS ----
  float b2l[8];
#pragma unroll
  for (int j = 0; j < 8; ++j) b2l[j] = b2[j * 64 + lane];
  float m2j[8];
#pragma unroll
  for (int j = 0; j < 8; ++j) m2j[j] = 0.0f;

#pragma unroll
  for (int t = 0; t < 25; ++t) {
#pragma unroll
    for (int j = 0; j < 8; ++j) {
      float cur = __fadd_rn(acc[t][j], b2l[j]);   // exact: same as cur2 store+load
      m2j[j] = leaky(m2j[j], cur);
      u64 ball = __ballot(m2j[j] > 1.0f);
      if (lane == 0) sbuf[w][t][j] = ball;
    }
  }

  // ---- layer 3 on lane 0: verified ascending-n ffs chain, low-reg region ----
  if (lane == 0) {
    const float b3v = b3[0];
    float m3 = 0.0f;
    double s3 = 0.0;
#pragma unroll 1
    for (int t = 0; t < 25; ++t) {
      float c3 = 0.0f;
#pragma unroll 1
      for (int j = 0; j < 8; ++j) {
        u64 mm = sbuf[w][t][j];
        const int nb = j * 64;
        if (mm) {
          int nn = __ffsll(mm) - 1;
          mm &= mm - 1;
          float wv = w3s[nb + nn];
          while (mm) {
            int n2 = __ffsll(mm) - 1;
            mm &= mm - 1;
            float wn = w3s[nb + n2];   // next load issued before dependent add
            c3 = __fadd_rn(c3, wv);
            wv = wn;
          }
          c3 = __fadd_rn(c3, wv);
        }
      }
      c3 = __fadd_rn(c3, b3v);
      m3 = leaky(m3, c3);
      s3 += (double)m3;
    }
    double z = s3 / 25.0;
    out[s0 + sl] = (float)(1.0 / (1.0 + exp(-z)));
  }
}

// ---------------------------------------------------------------------------
// Fallback: original verified single-kernel path (used if workspace too small)
// ---------------------------------------------------------------------------
__global__ __launch_bounds__(256) void k_snn(
    const float* __restrict__ x, const float* __restrict__ W1,
    const float* __restrict__ b1, const float* __restrict__ W2,
    const float* __restrict__ b2, const float* __restrict__ W3,
    const float* __restrict__ b3, float* __restrict__ out) {
  __shared__ float w1s[8 * 1024];
  __shared__ float w3s[512];
  __shared__ u32 spkm[4][32];
  const int tid = threadIdx.x, lane = tid & 63, w = tid >> 6;
  const size_t s = (size_t)blockIdx.x * 4 + w;

  for (int i = tid; i < 512; i += 256) w3s[i] = W3[i];

  float c1[16];
#pragma unroll
  for (int j = 0; j < 16; ++j) c1[j] = 0.0f;
#pragma unroll 1
  for (int ch = 0; ch < 8; ++ch) {
    __syncthreads();
#pragma unroll
    for (int it = 0; it < 8; ++it) {
      int v = tid + it * 256;
      *(f32x4*)(w1s + v * 4) =
          *(const f32x4*)(W1 + (size_t)(ch * 8 + (v >> 8)) * 1024 + (v & 255) * 4);
    }
    __syncthreads();
#pragma unroll 1
    for (int dl = 0; dl < 8; ++dl) {
      float xv = x[s * 64 + ch * 8 + dl];
#pragma unroll
      for (int j = 0; j < 16; ++j)
        c1[j] = fmaf(xv, w1s[dl * 1024 + j * 64 + lane], c1[j]);
    }
  }
#pragma unroll
  for (int j = 0; j < 16; ++j) c1[j] = __fadd_rn(c1[j], b1[j * 64 + lane]);

  float m1[16];
#pragma unroll
  for (int j = 0; j < 16; ++j) m1[j] = 0.0f;
  float m2[8];
#pragma unroll
  for (int j = 0; j < 8; ++j) m2[j] = 0.0f;
  float b2l[8];
#pragma unroll
  for (int j = 0; j < 8; ++j) b2l[j] = b2[j * 64 + lane];
  const float b3v = b3[0];
  float m3 = 0.0f;
  double s3 = 0.0;

#pragma unroll 1
  for (int t = 0; t < 25; ++t) {
#pragma unroll
    for (int j = 0; j < 16; ++j) {
      m1[j] = leaky(m1[j], c1[j]);
      u64 ball = __ballot(m1[j] > 1.0f);
      if (lane == 0) {
        spkm[w][2 * j]     = (u32)ball;
        spkm[w][2 * j + 1] = (u32)(ball >> 32);
      }
    }
    __syncthreads();

    float c2[8];
#pragma unroll
    for (int j = 0; j < 8; ++j) c2[j] = 0.0f;
#pragma unroll 1
    for (int kw = 0; kw < 32; ++kw) {
      u32 mask = spkm[w][kw];
      int kbase = kw * 32;
      while (mask) {
        int kk = __ffs(mask) - 1;
        mask &= mask - 1;
        const float* wr = W2 + (size_t)(kbase + kk) * 512;
#pragma unroll
        for (int j = 0; j < 8; ++j)
          c2[j] = __fadd_rn(c2[j], wr[j * 64 + lane]);
      }
    }
    u64 s2b[8];
#pragma unroll
    for (int j = 0; j < 8; ++j) {
      float cur = __fadd_rn(c2[j], b2l[j]);
      m2[j] = leaky(m2[j], cur);
      s2b[j] = __ballot(m2[j] > 1.0f);
    }

    if (lane == 0) {
      float c3 = 0.0f;
#pragma unroll 1
      for (int j = 0; j < 8; ++j) {
        u64 mm = s2b[j];
        int nb = j * 64;
        while (mm) {
          int nn = __ffsll(mm) - 1;
          mm &= mm - 1;
          c3 = __fadd_rn(c3, w3s[nb + nn]);
        }
      }
      c3 = __fadd_rn(c3, b3v);
      m3 = leaky(m3, c3);
      s3 += (double)m3;
    }
    __syncthreads();
  }

  if (lane == 0) {
    double z = s3 / 25.0;
    out[s] = (float)(1.0 / (1.0 + exp(-z)));
  }
}

extern "C" void kernel_launch(void* const* d_in, const int* in_sizes, int n_in,
                              void* d_out, int out_size, void* d_ws, size_t ws_size,
                              hipStream_t stream) {
  const float* x  = (const float*)d_in[0];
  const float* W1 = (const float*)d_in[1];
  const float* b1 = (const float*)d_in[2];
  const float* W2 = (const float*)d_in[3];
  const float* b2 = (const float*)d_in[4];
  const float* W3 = (const float*)d_in[5];
  const float* b3 = (const float*)d_in[6];
  float* out = (float*)d_out;

  // Workspace: per-sample spike words only — 1024 * 4 B = 4096 B.
  const long long per_sample = 4096;
  long long smax = (d_ws != nullptr) ? (long long)(ws_size / per_sample) : 0;
  long long scap = smax > 65536 ? 65536 : smax;
  int S = (int)(scap & ~63LL);

  if (S >= 256) {
    u32* masks2 = (u32*)d_ws;
    for (int s0 = 0; s0 < 65536; s0 += S) {
      int Sc = (65536 - s0 < S) ? (65536 - s0) : S;
      hipLaunchKernelGGL(k_spk1b, dim3(Sc / 4), dim3(256), 0, stream,
                         x, W1, b1, masks2, s0, Sc);
      hipLaunchKernelGGL(k_fused, dim3(Sc / 4), dim3(256), 0, stream,
                         W2, b2, W3, b3, masks2, out, s0, Sc);
    }
  } else {
    hipLaunchKernelGGL(k_snn, dim3(16384), dim3(256), 0, stream,
                       x, W1, b1, W2, b2, W3, b3, out);
  }
}

// Round 8
// 25548.801 us; speedup vs baseline: 1.5072x; 1.5072x over previous
//
#include <hip/hip_runtime.h>

typedef unsigned int u32;
typedef unsigned long long u64;
typedef float f32x4 __attribute__((ext_vector_type(4)));

// np-bit-exact Leaky update: m' = f32(f32(f32(0.95f*m) + cur) - reset)
// reset from PREVIOUS mem; (mem-1>0) === (mem>1) exactly in f32 (Sterbenz).
__device__ __forceinline__ float leaky(float m, float cur) {
  float r = (m > 1.0f) ? 1.0f : 0.0f;
  return __fsub_rn(__fadd_rn(__fmul_rn(0.95f, m), cur), r);
}

// ---------------------------------------------------------------------------
// Phase A: cur1 (exact FMA chain, d ascending) + layer-1 sim; emit per-step
// spike bitmasks to global in [t][kw][sample] layout (word kw covers
// k in [kw*32, kw*32+32), bit i <-> k = kw*32+i).
// Wave = 1 sample, block = 4 waves.   (unchanged — verified r1/r5/r6)
// ---------------------------------------------------------------------------
__global__ __launch_bounds__(256) void k_spk1(
    const float* __restrict__ x, const float* __restrict__ W1,
    const float* __restrict__ b1, u32* __restrict__ masks,
    int s0, int Sc) {
  __shared__ float w1s[8 * 1024];
  const int tid = threadIdx.x, lane = tid & 63, w = tid >> 6;
  const int sl = blockIdx.x * 4 + w;
  const size_t s = (size_t)s0 + sl;

  float c1[16];
#pragma unroll
  for (int j = 0; j < 16; ++j) c1[j] = 0.0f;
#pragma unroll 1
  for (int ch = 0; ch < 8; ++ch) {
    __syncthreads();
#pragma unroll
    for (int it = 0; it < 8; ++it) {
      int v = tid + it * 256;
      *(f32x4*)(w1s + v * 4) =
          *(const f32x4*)(W1 + (size_t)(ch * 8 + (v >> 8)) * 1024 + (v & 255) * 4);
    }
    __syncthreads();
#pragma unroll 1
    for (int dl = 0; dl < 8; ++dl) {
      float xv = x[s * 64 + ch * 8 + dl];
#pragma unroll
      for (int j = 0; j < 16; ++j)
        c1[j] = fmaf(xv, w1s[dl * 1024 + j * 64 + lane], c1[j]);
    }
  }
#pragma unroll
  for (int j = 0; j < 16; ++j) c1[j] = __fadd_rn(c1[j], b1[j * 64 + lane]);

  float m1[16];
#pragma unroll
  for (int j = 0; j < 16; ++j) m1[j] = 0.0f;

#pragma unroll 1
  for (int t = 0; t < 25; ++t) {
#pragma unroll
    for (int j = 0; j < 16; ++j) {
      m1[j] = leaky(m1[j], c1[j]);
      u64 ball = __ballot(m1[j] > 1.0f);
      if (lane == 0) {
        masks[((size_t)t * 32 + 2 * j) * Sc + sl] = (u32)ball;
        masks[((size_t)t * 32 + 2 * j + 1) * Sc + sl] = (u32)(ball >> 32);
      }
    }
  }
}

// ---------------------------------------------------------------------------
// Phase B: cur2 for 16 samples x 1 step per wave (4 waves/block, wave=task).
// k-outer shared row stream: each W2 row loaded ONCE per wave (2x dwordx4,
// n = lane*4 + q*256, 1KB coalesced per instr), amortized over 16 items ->
// L2 traffic 205 GB (~6 ms), under the 10.9 ms FP32-VALU floor.
// ROUND-7 LESSON (the allocator lever): long-lived f32x4 ext-vector values
// get demoted to AGPR blocks (r5/r6: VGPR_Count=56, v_accvgpr shuttle, 2.3x
// floor) while SCALAR float values get arch VGPRs (r7 k_fused: 172).
// => accumulators here are 128 NAMED SCALAR floats (macro-generated, all
// statically indexed). f32x4 is used ONLY for the short-lived row loads
// (load -> subreg extract -> dead).
// Gating stays the proven exact branchless chain: g = (bit?1.0f:0.0f) is a
// wave-uniform select; acc = fmaf(g, w, acc): fma(1,w,c)=RN add = BLAS step,
// fma(0,w,c)=c exactly. k ascending. ~165 regs -> 3 waves/SIMD.
// ---------------------------------------------------------------------------
#define FOR16(M) M(0) M(1) M(2) M(3) M(4) M(5) M(6) M(7) \
                 M(8) M(9) M(10) M(11) M(12) M(13) M(14) M(15)

#define DECL_ACC(i)                                                     \
  float aA##i##_0 = 0.f, aA##i##_1 = 0.f, aA##i##_2 = 0.f, aA##i##_3 = 0.f; \
  float aB##i##_0 = 0.f, aB##i##_1 = 0.f, aB##i##_2 = 0.f, aB##i##_3 = 0.f;

#define LOADW(i) const u32 w##i = (u32)__builtin_amdgcn_readfirstlane((int)mp[i]);

#define E4(A, R, g) A##_0 = fmaf(g, R[0], A##_0); A##_1 = fmaf(g, R[1], A##_1); \
                    A##_2 = fmaf(g, R[2], A##_2); A##_3 = fmaf(g, R[3], A##_3);

#define GFMA_A(i) { const float g = (w##i & mA) ? 1.0f : 0.0f; \
                    E4(aA##i, rA0, g) E4(aB##i, rA1, g) }
#define GFMA_B(i) { const float g = (w##i & mB) ? 1.0f : 0.0f; \
                    E4(aA##i, rB0, g) E4(aB##i, rB1, g) }

#define STORE16(i) {                                                    \
  float* op = cur2 + ((size_t)(sl0 + i) * 25 + t) * 512 + lq;           \
  op[0] = __fadd_rn(aA##i##_0, bv0); op[1] = __fadd_rn(aA##i##_1, bv1); \
  op[2] = __fadd_rn(aA##i##_2, bv2); op[3] = __fadd_rn(aA##i##_3, bv3); \
  op[256] = __fadd_rn(aB##i##_0, bv4); op[257] = __fadd_rn(aB##i##_1, bv5); \
  op[258] = __fadd_rn(aB##i##_2, bv6); op[259] = __fadd_rn(aB##i##_3, bv7); }

__global__ __launch_bounds__(256) void k_cur2(
    const float* __restrict__ W2, const float* __restrict__ b2,
    const u32* __restrict__ masks, float* __restrict__ cur2, int Sc) {
  const int tid = threadIdx.x, lane = tid & 63, w = tid >> 6;
  const int task = blockIdx.x * 4 + w;    // grid = (Sc/16)*25/4 blocks
  const int grp = task / 25, t = task - grp * 25;
  const int sl0 = grp * 16;
  const int lq = lane * 4;

  FOR16(DECL_ACC)

  const float* wp = W2 + lq;              // row k quad0 at wp+k*512, quad1 +256
  f32x4 rA0 = *(const f32x4*)(wp);
  f32x4 rA1 = *(const f32x4*)(wp + 256);
  f32x4 rB0, rB1;

#pragma unroll 1
  for (int kw = 0; kw < 32; ++kw) {
    const u32* mp = masks + ((size_t)t * 32 + kw) * Sc + sl0;
    FOR16(LOADW)
#pragma unroll 1
    for (int k2 = 0; k2 < 32; k2 += 2) {
      const int k = kw * 32 + k2;
      const u32 mA = 1u << k2;            // one s_lshl, shared by 16 gates
      const u32 mB = 2u << k2;
      const float* pB = wp + (size_t)(k + 1) * 512;   // prefetch row k+1
      rB0 = *(const f32x4*)(pB);
      rB1 = *(const f32x4*)(pB + 256);
      FOR16(GFMA_A)                       // row k applied before row k+1
      const int kn = (k + 2 < 1024) ? k + 2 : 1023;   // harmless clamp at tail
      const float* pA = wp + (size_t)kn * 512;        // prefetch row k+2
      rA0 = *(const f32x4*)(pA);
      rA1 = *(const f32x4*)(pA + 256);
      FOR16(GFMA_B)
    }
  }

  const float bv0 = b2[lq], bv1 = b2[lq + 1], bv2 = b2[lq + 2], bv3 = b2[lq + 3];
  const float bv4 = b2[256 + lq], bv5 = b2[257 + lq];
  const float bv6 = b2[258 + lq], bv7 = b2[259 + lq];
  FOR16(STORE16)
}

// ---------------------------------------------------------------------------
// Phase C: layers 2-3 recurrence off stored cur2 (exact f32 round-trip).
// Wave = 1 sample; n = j*64+lane mapping so ballots give n-ordered words;
// lane-0 ascending-n ffs chain with 1-deep LDS-load pipeline.
// Mean+sigmoid in f64.   (unchanged — verified)
// ---------------------------------------------------------------------------
__global__ __launch_bounds__(256) void k_tail(
    const float* __restrict__ cur2, const float* __restrict__ W3,
    const float* __restrict__ b3, float* __restrict__ out, int s0, int Sc) {
  __shared__ float w3s[512];
  const int tid = threadIdx.x, lane = tid & 63, w = tid >> 6;
  const int sl = blockIdx.x * 4 + w;
  for (int i = tid; i < 512; i += 256) w3s[i] = W3[i];
  __syncthreads();

  float m2[8];
#pragma unroll
  for (int j = 0; j < 8; ++j) m2[j] = 0.0f;
  float m3 = 0.0f;
  double s3 = 0.0;
  const float b3v = b3[0];
  const float* cp = cur2 + (size_t)sl * 25 * 512;

#pragma unroll 1
  for (int t = 0; t < 25; ++t) {
    u64 s2b[8];
#pragma unroll
    for (int j = 0; j < 8; ++j) {
      float cur = cp[t * 512 + j * 64 + lane];
      m2[j] = leaky(m2[j], cur);
      s2b[j] = __ballot(m2[j] > 1.0f);
    }
    if (lane == 0) {
      float c3 = 0.0f;
#pragma unroll 1
      for (int j = 0; j < 8; ++j) {
        u64 mm = s2b[j];
        const int nb = j * 64;
        if (mm) {
          int nn = __ffsll(mm) - 1;
          mm &= mm - 1;
          float wv = w3s[nb + nn];
          while (mm) {
            int n2 = __ffsll(mm) - 1;
            mm &= mm - 1;
            float wn = w3s[nb + n2];   // next load issued before dependent add
            c3 = __fadd_rn(c3, wv);
            wv = wn;
          }
          c3 = __fadd_rn(c3, wv);
        }
      }
      c3 = __fadd_rn(c3, b3v);
      m3 = leaky(m3, c3);
      s3 += (double)m3;
    }
  }
  if (lane == 0) {
    double z = s3 / 25.0;
    out[s0 + sl] = (float)(1.0 / (1.0 + exp(-z)));
  }
}

// ---------------------------------------------------------------------------
// Fallback: original verified single-kernel path (used if workspace too small)
// ---------------------------------------------------------------------------
__global__ __launch_bounds__(256) void k_snn(
    const float* __restrict__ x, const float* __restrict__ W1,
    const float* __restrict__ b1, const float* __restrict__ W2,
    const float* __restrict__ b2, const float* __restrict__ W3,
    const float* __restrict__ b3, float* __restrict__ out) {
  __shared__ float w1s[8 * 1024];
  __shared__ float w3s[512];
  __shared__ u32 spkm[4][32];
  const int tid = threadIdx.x, lane = tid & 63, w = tid >> 6;
  const size_t s = (size_t)blockIdx.x * 4 + w;

  for (int i = tid; i < 512; i += 256) w3s[i] = W3[i];

  float c1[16];
#pragma unroll
  for (int j = 0; j < 16; ++j) c1[j] = 0.0f;
#pragma unroll 1
  for (int ch = 0; ch < 8; ++ch) {
    __syncthreads();
#pragma unroll
    for (int it = 0; it < 8; ++it) {
      int v = tid + it * 256;
      *(f32x4*)(w1s + v * 4) =
          *(const f32x4*)(W1 + (size_t)(ch * 8 + (v >> 8)) * 1024 + (v & 255) * 4);
    }
    __syncthreads();
#pragma unroll 1
    for (int dl = 0; dl < 8; ++dl) {
      float xv = x[s * 64 + ch * 8 + dl];
#pragma unroll
      for (int j = 0; j < 16; ++j)
        c1[j] = fmaf(xv, w1s[dl * 1024 + j * 64 + lane], c1[j]);
    }
  }
#pragma unroll
  for (int j = 0; j < 16; ++j) c1[j] = __fadd_rn(c1[j], b1[j * 64 + lane]);

  float m1[16];
#pragma unroll
  for (int j = 0; j < 16; ++j) m1[j] = 0.0f;
  float m2[8];
#pragma unroll
  for (int j = 0; j < 8; ++j) m2[j] = 0.0f;
  float b2l[8];
#pragma unroll
  for (int j = 0; j < 8; ++j) b2l[j] = b2[j * 64 + lane];
  const float b3v = b3[0];
  float m3 = 0.0f;
  double s3 = 0.0;

#pragma unroll 1
  for (int t = 0; t < 25; ++t) {
#pragma unroll
    for (int j = 0; j < 16; ++j) {
      m1[j] = leaky(m1[j], c1[j]);
      u64 ball = __ballot(m1[j] > 1.0f);
      if (lane == 0) {
        spkm[w][2 * j]     = (u32)ball;
        spkm[w][2 * j + 1] = (u32)(ball >> 32);
      }
    }
    __syncthreads();

    float c2[8];
#pragma unroll
    for (int j = 0; j < 8; ++j) c2[j] = 0.0f;
#pragma unroll 1
    for (int kw = 0; kw < 32; ++kw) {
      u32 mask = spkm[w][kw];
      int kbase = kw * 32;
      while (mask) {
        int kk = __ffs(mask) - 1;
        mask &= mask - 1;
        const float* wr = W2 + (size_t)(kbase + kk) * 512;
#pragma unroll
        for (int j = 0; j < 8; ++j)
          c2[j] = __fadd_rn(c2[j], wr[j * 64 + lane]);
      }
    }
    u64 s2b[8];
#pragma unroll
    for (int j = 0; j < 8; ++j) {
      float cur = __fadd_rn(c2[j], b2l[j]);
      m2[j] = leaky(m2[j], cur);
      s2b[j] = __ballot(m2[j] > 1.0f);
    }

    if (lane == 0) {
      float c3 = 0.0f;
#pragma unroll 1
      for (int j = 0; j < 8; ++j) {
        u64 mm = s2b[j];
        int nb = j * 64;
        while (mm) {
          int nn = __ffsll(mm) - 1;
          mm &= mm - 1;
          c3 = __fadd_rn(c3, w3s[nb + nn]);
        }
      }
      c3 = __fadd_rn(c3, b3v);
      m3 = leaky(m3, c3);
      s3 += (double)m3;
    }
    __syncthreads();
  }

  if (lane == 0) {
    double z = s3 / 25.0;
    out[s] = (float)(1.0 / (1.0 + exp(-z)));
  }
}

extern "C" void kernel_launch(void* const* d_in, const int* in_sizes, int n_in,
                              void* d_out, int out_size, void* d_ws, size_t ws_size,
                              hipStream_t stream) {
  const float* x  = (const float*)d_in[0];
  const float* W1 = (const float*)d_in[1];
  const float* b1 = (const float*)d_in[2];
  const float* W2 = (const float*)d_in[3];
  const float* b2 = (const float*)d_in[4];
  const float* W3 = (const float*)d_in[5];
  const float* b3 = (const float*)d_in[6];
  float* out = (float*)d_out;

  // Per-sample workspace: masks 25*32*4 = 3200 B, cur2 25*512*4 = 51200 B.
  const long long per_sample = 54400;
  long long smax = (d_ws != nullptr) ? (long long)(ws_size / per_sample) : 0;
  long long scap = smax > 65536 ? 65536 : smax;
  int S = (int)(scap & ~63LL);

  if (S >= 256) {
    u32* masks = (u32*)d_ws;
    float* cur2 = (float*)((char*)d_ws + (size_t)S * 3200);
    for (int s0 = 0; s0 < 65536; s0 += S) {
      int Sc = (65536 - s0 < S) ? (65536 - s0) : S;
      hipLaunchKernelGGL(k_spk1, dim3(Sc / 4), dim3(256), 0, stream,
                         x, W1, b1, masks, s0, Sc);
      hipLaunchKernelGGL(k_cur2, dim3(((Sc / 16) * 25) / 4), dim3(256), 0, stream,
                         W2, b2, masks, cur2, Sc);
      hipLaunchKernelGGL(k_tail, dim3(Sc / 4), dim3(256), 0, stream,
                         cur2, W3, b3, out, s0, Sc);
    }
  } else {
    hipLaunchKernelGGL(k_snn, dim3(16384), dim3(256), 0, stream,
                       x, W1, b1, W2, b2, W3, b3, out);
  }
}